// Round 13
// baseline (251.784 us; speedup 1.0000x reference)
//
#include <hip/hip_runtime.h>
#include <hip/hip_bf16.h>

// Problem constants: N=2, L=2048, S=2048, D=128, H=32
#define N_B 2
#define L_Q 2048
#define S_S 2048
#define D_D 128
#define H_H 32
// 1/sqrt(128) * log2(e), folded into K projection so attn uses exp2 directly
#define SCALEK (0.08838834764831845f * 1.4426950408889634f)

typedef __attribute__((ext_vector_type(8))) short bf8;   // 8 bf16 (4 VGPR)
typedef __attribute__((ext_vector_type(4))) short bf4;   // 4 bf16 (2 VGPR)
typedef __attribute__((ext_vector_type(4))) float f4;    // 4 f32

#define MFMA(a, b, c) __builtin_amdgcn_mfma_f32_16x16x32_bf16(a, b, c, 0, 0, 0)

__device__ __forceinline__ short f2bf(float x) {
    union { float f; unsigned u; } v; v.f = x;
    unsigned r = v.u + 0x7FFFu + ((v.u >> 16) & 1u);   // RNE
    return (short)(r >> 16);
}

// pack 4 f32 -> 4 bf16 (RNE) via v_cvt_pk_bf16_f32 (compiler-lowered)
__device__ __forceinline__ bf4 pk4(float a, float b, float c, float d) {
    union { __hip_bfloat162 h2[2]; bf4 v; } u;
    u.h2[0] = __float22bfloat162_rn(make_float2(a, b));
    u.h2[1] = __float22bfloat162_rn(make_float2(c, d));
    return u.v;
}

__device__ __forceinline__ bf8 cat44(bf4 lo, bf4 hi) {
    bf8 r;
    r[0] = lo[0]; r[1] = lo[1]; r[2] = lo[2]; r[3] = lo[3];
    r[4] = hi[0]; r[5] = hi[1]; r[6] = hi[2]; r[7] = hi[3];
    return r;
}

// 8 consecutive f32 from global -> bf16x8 fragment
__device__ __forceinline__ bf8 load8(const float* p) {
    const float4* q = (const float4*)p;
    float4 a = q[0], b = q[1];
    bf8 r;
    r[0] = f2bf(a.x); r[1] = f2bf(a.y); r[2] = f2bf(a.z); r[3] = f2bf(a.w);
    r[4] = f2bf(b.x); r[5] = f2bf(b.y); r[6] = f2bf(b.z); r[7] = f2bf(b.w);
    return r;
}

// async global->LDS, 16B per lane. lds dst must be wave-uniform base (+lane*16 implicit)
__device__ __forceinline__ void async16(const void* g, void* l) {
    __builtin_amdgcn_global_load_lds(
        (const __attribute__((address_space(1))) unsigned*)g,
        (__attribute__((address_space(3))) unsigned*)l, 16, 0, 0);
}

// ---------------- Kernel A: Wc [4096][128] f32 -> WcF fragment layout ----------------
__global__ __launch_bounds__(256) void k_wct(const float* __restrict__ Wc,
                                             unsigned short* __restrict__ WcF) {
    int f16 = blockIdx.x * 256 + threadIdx.x;   // 65536 fragments
    int l = f16 & 63, t = (f16 >> 6) & 3, nfA = (f16 >> 8) & 7, kc = f16 >> 11;
    int lrow = l & 15, lgrp = l >> 4;
    int kbase = kc * 128 + t * 32 + lgrp * 8;
    int n = nfA * 16 + lrow;
    bf8 v;
    #pragma unroll
    for (int j = 0; j < 8; ++j) v[j] = f2bf(Wc[(size_t)(kbase + j) * D_D + n]);
    *(bf8*)(WcF + (size_t)f16 * 8) = v;
}

// ---------------- Kernel A2: W[h][k][d] f32 -> WF fragment layout (Wk and Wv) --------
__global__ __launch_bounds__(256) void k_wt(const float* __restrict__ Wk,
        const float* __restrict__ Wv, unsigned short* __restrict__ WkF,
        unsigned short* __restrict__ WvF) {
    __shared__ unsigned short T[128][129];
    const int tid = threadIdx.x;
    const int h = blockIdx.x;
    const int job = blockIdx.y;
    const float* W = (job ? Wv : Wk) + (size_t)h * (D_D * D_D);
    unsigned short* WF = (job ? WvF : WkF) + (size_t)h * (D_D * D_D);

    #pragma unroll
    for (int i = 0; i < 64; ++i) {
        int flat = i * 256 + tid;       // k*128 + d
        T[flat >> 7][flat & 127] = (unsigned short)f2bf(W[flat]);
    }
    __syncthreads();
    #pragma unroll
    for (int j8 = 0; j8 < 8; ++j8) {
        int f16 = j8 * 256 + tid;
        int l = f16 & 63, t = (f16 >> 6) & 3, df = (f16 >> 8) & 7;
        int lrow = l & 15, lgrp = l >> 4;
        bf8 v;
        #pragma unroll
        for (int j = 0; j < 8; ++j) v[j] = (short)T[t * 32 + lgrp * 8 + j][df * 16 + lrow];
        *(bf8*)(WF + (size_t)f16 * 8) = v;
    }
}

// ---------------- Kernel B: FUSED K/V projections, packed 8B stores ------------------
// (unchanged from R11/R12 -- others at 59-62us with this version)
__global__ __launch_bounds__(256) void k_proj(const float* __restrict__ states,
        const unsigned short* __restrict__ WkF, const float* __restrict__ bk,
        const unsigned short* __restrict__ WvF, const float* __restrict__ bv,
        unsigned short* __restrict__ Kb, unsigned short* __restrict__ VTb) {
    const int tid = threadIdx.x;
    const int l = tid & 63, w = tid >> 6;
    const int lrow = l & 15, lgrp = l >> 4;
    const int bx = blockIdx.x;                  // (n*H + h)*32 + sc
    const int sc = bx & 31;
    const int nh = bx >> 5;
    const int h = nh & 31, n = nh >> 5;

    const float* srow = states + ((size_t)n * S_S + sc * 64 + w * 16 + lrow) * D_D;
    bf8 sf[4];
    #pragma unroll
    for (int t = 0; t < 4; ++t) sf[t] = load8(srow + t * 32 + lgrp * 8);

    // K job: swapped (A=WkF m=d, B=states n=s) -> 4 consecutive d per lane -> 8B stores
    {
        const unsigned short* WF = WkF + (size_t)h * (D_D * D_D);
        f4 acc[8];
        #pragma unroll
        for (int i = 0; i < 8; ++i) acc[i] = (f4)(0.f);
        #pragma unroll
        for (int mf = 0; mf < 8; ++mf) {
            #pragma unroll
            for (int t = 0; t < 4; ++t) {
                bf8 a = *(const bf8*)(WF + (((mf * 4 + t) * 64 + l) << 3));
                acc[mf] = MFMA(a, sf[t], acc[mf]);
            }
        }
        unsigned short* Kout = Kb + (size_t)(n * H_H + h) * S_S * D_D
                                  + (size_t)(sc * 64 + w * 16 + lrow) * D_D;
        #pragma unroll
        for (int mf = 0; mf < 8; ++mf) {
            int d0 = mf * 16 + lgrp * 4;
            float4 bb = *(const float4*)(bk + h * D_D + d0);
            bf4 kv = pk4((acc[mf][0] + bb.x) * SCALEK, (acc[mf][1] + bb.y) * SCALEK,
                         (acc[mf][2] + bb.z) * SCALEK, (acc[mf][3] + bb.w) * SCALEK);
            *(bf4*)(Kout + d0) = kv;
        }
    }
    // V job: non-swapped -> 4 consecutive permuted-s per lane -> 8B stores
    {
        const unsigned short* WF = WvF + (size_t)h * (D_D * D_D);
        f4 acc[8];
        #pragma unroll
        for (int i = 0; i < 8; ++i) acc[i] = (f4)(0.f);
        #pragma unroll
        for (int nf = 0; nf < 8; ++nf) {
            #pragma unroll
            for (int t = 0; t < 4; ++t) {
                bf8 b = *(const bf8*)(WF + (((nf * 4 + t) * 64 + l) << 3));
                acc[nf] = MFMA(sf[t], b, acc[nf]);
            }
        }
        unsigned short* Vout = VTb + (size_t)(n * H_H + h) * D_D * S_S;
        const int p0 = ((w >> 1) << 5) + (lgrp << 3) + ((w & 1) << 2);
        #pragma unroll
        for (int nf = 0; nf < 8; ++nf) {
            int d = nf * 16 + lrow;
            float bias = bv[h * D_D + d];
            bf4 vv = pk4(acc[nf][0] + bias, acc[nf][1] + bias,
                         acc[nf][2] + bias, acc[nf][3] + bias);
            *(bf4*)(Vout + (size_t)d * S_S + sc * 64 + p0) = vv;
        }
    }
}

// ---------------- Kernel C: flash attention, 3-buffer counted-vmcnt pipeline --------
// R12 post-mortem: wall = zero-overlap serial sum scaled by resident waves; R10's
// 12-wave config ran LDS pipe at only 70% duty. The stall is the 2-phase structure:
// __syncthreads emits s_waitcnt vmcnt(0) -> every iter drains the prefetch queue
// (m233). Fix (T3+T4): 3 LDS buffers, raw s_barrier, counted s_waitcnt vmcnt(4) --
// NEVER 0 in the main loop. stage(i+2) issues right after the barrier and has ~2
// full iterations to land. WAR safe: buf (i+2)%3 last read at iter i-1, whose
// ds_reads are consumed (lgkm-waited before MFMA use) before the barrier.
__global__ __launch_bounds__(256, 3) void k_attn(const float* __restrict__ query,
        const unsigned short* __restrict__ Kb, const unsigned short* __restrict__ VTb,
        unsigned short* __restrict__ CTX) {
    // LDS 48KB: Kbuf[3] @ 0 ([32 s][256B] swz), Vbuf[3] @ 24576 ([128 d][64B] swz)
    __shared__ char smem[49152];
    const int tid = threadIdx.x;
    const int l = tid & 63, w = tid >> 6;          // w = 0..3
    const int lrow = l & 15, lgrp = l >> 4;

    // XCD swizzle: 1024 blocks, 8 XCDs -> 128 consecutive work-ids per XCD
    const int bid = blockIdx.x;
    const int bx = (bid & 7) * 128 + (bid >> 3);
    const int qt = bx & 15;
    const int nh = bx >> 4;
    const int h = nh & 31, n = nh >> 5;
    const int qbase = qt * 128 + w * 32;

    // Q fragments as B-operand of swapped QK^T
    bf8 qf[2][4];
    #pragma unroll
    for (int mf = 0; mf < 2; ++mf) {
        const float* qp = query + ((size_t)n * L_Q + qbase + mf * 16 + lrow) * D_D;
        #pragma unroll
        for (int t = 0; t < 4; ++t) qf[mf][t] = load8(qp + t * 32 + lgrp * 8);
    }

    f4 oacc[2][8];   // O^T[d][q]: lane holds rows d = df*16 + 4*lgrp + r, col q = lrow
    #pragma unroll
    for (int mf = 0; mf < 2; ++mf)
        #pragma unroll
        for (int df = 0; df < 8; ++df) oacc[mf][df] = (f4)(0.f);
    float rsum[2] = {0.f, 0.f};

    const char* Kg = (const char*)(Kb + (size_t)(n * H_H + h) * S_S * D_D);
    const char* Vg = (const char*)(VTb + (size_t)(n * H_H + h) * D_D * S_S);

    // stage 32-s chunk sc2 (0..63) into buffer c: K 8KB + V 8KB, 4 async16 per wave
    auto stage = [&](int c, int sc2) {
        char* Kl = smem + c * 8192;
        char* Vl = smem + 24576 + c * 8192;
        #pragma unroll
        for (int i = 0; i < 2; ++i) {
            int kop = w * 2 + i;                 // 0..7
            int o = kop * 1024 + l * 16;         // 0..8191
            int r = o >> 8;                      // s-row 0..31
            int b = (o & 255) ^ ((r & 7) << 4);
            async16(Kg + (size_t)(sc2 * 32 + r) * 256 + b, Kl + kop * 1024);
        }
        #pragma unroll
        for (int i = 0; i < 2; ++i) {
            int vop = w * 2 + i;
            int o = vop * 1024 + l * 16;         // 0..8191
            int drow = o >> 6;                   // d-row 0..127 (64B rows)
            int b = (o & 63) ^ (((drow >> 1) & 3) << 4);
            async16(Vg + (size_t)drow * 4096 + sc2 * 64 + b, Vl + vop * 1024);
        }
    };

    // compute on buffer `cur` for chunk sc2; optionally stage chunk sc2+2 into `nxt`
    auto iter = [&](int cur, int nxt, int sc2) {
        // counted wait: chunk sc2's 4 loads landed; next chunk's 4 may stay in flight
        asm volatile("s_waitcnt vmcnt(4)" ::: "memory");
        __builtin_amdgcn_s_barrier();
        __builtin_amdgcn_sched_barrier(0);
        if (sc2 + 2 < 64) stage(nxt, sc2 + 2);
        const char* Klds = smem + cur * 8192;
        const char* Vlds = smem + 24576 + cur * 8192;

        // QK^T swapped: sacc[mf][nf] over 32 s
        f4 sacc[2][2];
        #pragma unroll
        for (int mf = 0; mf < 2; ++mf)
            #pragma unroll
            for (int nf = 0; nf < 2; ++nf) sacc[mf][nf] = (f4)(0.f);
        __builtin_amdgcn_s_setprio(1);
        #pragma unroll
        for (int nf = 0; nf < 2; ++nf) {
            int srow = nf * 16 + lrow;
            int swz = (srow & 7) << 4;
            #pragma unroll
            for (int t = 0; t < 4; ++t) {
                bf8 kb = *(const bf8*)(Klds + srow * 256 + (((t * 32 + lgrp * 8) * 2) ^ swz));
                sacc[0][nf] = MFMA(kb, qf[0][t], sacc[0][nf]);
                sacc[1][nf] = MFMA(kb, qf[1][t], sacc[1][nf]);
            }
        }
        __builtin_amdgcn_s_setprio(0);

        // softmax: exp2 + lane-local sum + pack into ONE K=32 B-operand per mf
        bf8 pf[2];
        #pragma unroll
        for (int mf = 0; mf < 2; ++mf) {
            bf4 pblk[2];
            #pragma unroll
            for (int nf = 0; nf < 2; ++nf) {
                float p0 = __builtin_amdgcn_exp2f(sacc[mf][nf][0]);
                float p1 = __builtin_amdgcn_exp2f(sacc[mf][nf][1]);
                float p2 = __builtin_amdgcn_exp2f(sacc[mf][nf][2]);
                float p3 = __builtin_amdgcn_exp2f(sacc[mf][nf][3]);
                rsum[mf] += (p0 + p1) + (p2 + p3);
                pblk[nf] = pk4(p0, p1, p2, p3);
            }
            pf[mf] = cat44(pblk[0], pblk[1]);
        }

        // PV swapped, K=32: V^T s-permuted -> ONE conflict-free b128 per df
        __builtin_amdgcn_s_setprio(1);
        #pragma unroll
        for (int df = 0; df < 8; ++df) {
            int drow = df * 16 + lrow;
            bf8 vf = *(const bf8*)(Vlds + drow * 64 + ((lgrp * 16) ^ (((drow >> 1) & 3) << 4)));
            oacc[0][df] = MFMA(vf, pf[0], oacc[0][df]);
            oacc[1][df] = MFMA(vf, pf[1], oacc[1][df]);
        }
        __builtin_amdgcn_s_setprio(0);
        // NO trailing barrier, NO vmcnt(0): next iter's counted wait handles it
    };

    stage(0, 0);
    stage(1, 1);
    // 63 iters in 21 unrolled-by-3 rounds (static buffer indices), tail iter 63
    for (int i3 = 0; i3 < 63; i3 += 3) {
        iter(0, 2, i3);
        iter(1, 0, i3 + 1);
        iter(2, 1, i3 + 2);
    }
    {   // tail: chunk 63 in buf 0; must drain fully (only 4 loads outstanding)
        asm volatile("s_waitcnt vmcnt(0)" ::: "memory");
        __builtin_amdgcn_s_barrier();
        __builtin_amdgcn_sched_barrier(0);
        const char* Klds = smem;
        const char* Vlds = smem + 24576;
        f4 sacc[2][2];
        #pragma unroll
        for (int mf = 0; mf < 2; ++mf)
            #pragma unroll
            for (int nf = 0; nf < 2; ++nf) sacc[mf][nf] = (f4)(0.f);
        #pragma unroll
        for (int nf = 0; nf < 2; ++nf) {
            int srow = nf * 16 + lrow;
            int swz = (srow & 7) << 4;
            #pragma unroll
            for (int t = 0; t < 4; ++t) {
                bf8 kb = *(const bf8*)(Klds + srow * 256 + (((t * 32 + lgrp * 8) * 2) ^ swz));
                sacc[0][nf] = MFMA(kb, qf[0][t], sacc[0][nf]);
                sacc[1][nf] = MFMA(kb, qf[1][t], sacc[1][nf]);
            }
        }
        bf8 pf[2];
        #pragma unroll
        for (int mf = 0; mf < 2; ++mf) {
            bf4 pblk[2];
            #pragma unroll
            for (int nf = 0; nf < 2; ++nf) {
                float p0 = __builtin_amdgcn_exp2f(sacc[mf][nf][0]);
                float p1 = __builtin_amdgcn_exp2f(sacc[mf][nf][1]);
                float p2 = __builtin_amdgcn_exp2f(sacc[mf][nf][2]);
                float p3 = __builtin_amdgcn_exp2f(sacc[mf][nf][3]);
                rsum[mf] += (p0 + p1) + (p2 + p3);
                pblk[nf] = pk4(p0, p1, p2, p3);
            }
            pf[mf] = cat44(pblk[0], pblk[1]);
        }
        #pragma unroll
        for (int df = 0; df < 8; ++df) {
            int drow = df * 16 + lrow;
            bf8 vf = *(const bf8*)(Vlds + drow * 64 + ((lgrp * 16) ^ (((drow >> 1) & 3) << 4)));
            oacc[0][df] = MFMA(vf, pf[0], oacc[0][df]);
            oacc[1][df] = MFMA(vf, pf[1], oacc[1][df]);
        }
    }

    // reduce rsum over the 4 lane-groups; q = lrow stays lane-local
    float rinv[2];
    #pragma unroll
    for (int mf = 0; mf < 2; ++mf) {
        float v = rsum[mf];
        v += __shfl_xor(v, 16, 64);
        v += __shfl_xor(v, 32, 64);
        rinv[mf] = 1.f / v;
    }
    #pragma unroll
    for (int mf = 0; mf < 2; ++mf) {
        int qrow = qbase + mf * 16 + lrow;
        unsigned short* crow = CTX + (size_t)(n * L_Q + qrow) * 4096 + h * D_D;
        #pragma unroll
        for (int df = 0; df < 8; ++df) {
            bf4 o = pk4(oacc[mf][df][0] * rinv[mf], oacc[mf][df][1] * rinv[mf],
                        oacc[mf][df][2] * rinv[mf], oacc[mf][df][3] * rinv[mf]);
            *(bf4*)(crow + df * 16 + lgrp * 4) = o;
        }
    }
}

// ---------------- Kernel E: out = CTX @ Wc + bc (M=16, 256 blocks, coalesced WcF) ---
__global__ __launch_bounds__(256) void k_out(const unsigned short* __restrict__ CTX,
        const unsigned short* __restrict__ WcF, const float* __restrict__ bc,
        float* __restrict__ out) {
    __shared__ char Alds[8192];   // 2 x [16][256B] swizzled
    const int tid = threadIdx.x;
    const int l = tid & 63, w = tid >> 6;
    const int lrow = l & 15, lgrp = l >> 4;
    const int m0 = blockIdx.x * 16;      // 256 blocks
    const char* Ag = (const char*)(CTX + (size_t)m0 * 4096);

    auto stage = [&](int c, int kc) {
        int o = w * 1024 + l * 16;
        int r = o >> 8;
        int b = (o & 255) ^ ((r & 7) << 4);
        async16(Ag + (size_t)r * 8192 + kc * 256 + b, Alds + c * 4096 + w * 1024);
    };

    f4 acc[2];
    acc[0] = (f4)(0.f); acc[1] = (f4)(0.f);
    stage(0, 0);
    __syncthreads();
    int cur = 0;
    for (int kc = 0; kc < 32; ++kc) {
        if (kc < 31) stage(cur ^ 1, kc + 1);
        const char* Ac = Alds + cur * 4096;
        #pragma unroll
        for (int t = 0; t < 4; ++t) {
            int swz = (lrow & 7) << 4;
            bf8 a = *(const bf8*)(Ac + lrow * 256 + (((t * 32 + lgrp * 8) * 2) ^ swz));
            #pragma unroll
            for (int nf = 0; nf < 2; ++nf) {
                int nfA = w * 2 + nf;
                bf8 b = *(const bf8*)(WcF + ((size_t)(((kc * 8 + nfA) * 4 + t) * 64 + l) << 3));
                acc[nf] = MFMA(a, b, acc[nf]);
            }
        }
        __syncthreads();
        cur ^= 1;
    }
    #pragma unroll
    for (int nf = 0; nf < 2; ++nf) {
        int nc = w * 32 + nf * 16 + lrow;
        float bias = bc[nc];
        #pragma unroll
        for (int r = 0; r < 4; ++r)
            out[(size_t)(m0 + lgrp * 4 + r) * D_D + nc] = acc[nf][r] + bias;
    }
}

extern "C" void kernel_launch(void* const* d_in, const int* in_sizes, int n_in,
                              void* d_out, int out_size, void* d_ws, size_t ws_size,
                              hipStream_t stream) {
    const float* query  = (const float*)d_in[0];
    const float* states = (const float*)d_in[1];
    const float* Wk = (const float*)d_in[2];
    const float* bk = (const float*)d_in[3];
    const float* Wv = (const float*)d_in[4];
    const float* bv = (const float*)d_in[5];
    const float* Wc = (const float*)d_in[6];
    const float* bc = (const float*)d_in[7];
    float* out = (float*)d_out;

    // workspace (bf16): Kb 32MB | VTb 32MB | CTX 32MB | WcF 1MB.
    // WkF/WvF (1MB each) OVERLAP the CTX region: consumed by k_proj before
    // k_attn writes CTX -> no extra ws.
    char* ws = (char*)d_ws;
    unsigned short* Kb  = (unsigned short*)(ws);
    unsigned short* VTb = (unsigned short*)(ws + 33554432);
    unsigned short* CTX = (unsigned short*)(ws + 67108864);
    unsigned short* WkF = (unsigned short*)(ws + 67108864);
    unsigned short* WvF = (unsigned short*)(ws + 67108864 + 1048576);
    unsigned short* WcF = (unsigned short*)(ws + 100663296);

    k_wct<<<256, 256, 0, stream>>>(Wc, WcF);
    dim3 gw(32, 2);
    k_wt<<<gw, 256, 0, stream>>>(Wk, Wv, WkF, WvF);
    k_proj<<<2048, 256, 0, stream>>>(states, WkF, bk, WvF, bv, Kb, VTb);
    k_attn<<<1024, 256, 0, stream>>>(query, Kb, VTb, CTX);
    k_out<<<256, 256, 0, stream>>>(CTX, WcF, bc, out);
}

// Round 14
// 220.955 us; speedup vs baseline: 1.1395x; 1.1395x over previous
//
#include <hip/hip_runtime.h>
#include <hip/hip_bf16.h>

// Problem constants: N=2, L=2048, S=2048, D=128, H=32
#define N_B 2
#define L_Q 2048
#define S_S 2048
#define D_D 128
#define H_H 32
// 1/sqrt(128) * log2(e), folded into K projection so attn uses exp2 directly
#define SCALEK (0.08838834764831845f * 1.4426950408889634f)

typedef __attribute__((ext_vector_type(8))) short bf8;   // 8 bf16 (4 VGPR)
typedef __attribute__((ext_vector_type(4))) short bf4;   // 4 bf16 (2 VGPR)
typedef __attribute__((ext_vector_type(4))) float f4;    // 4 f32

#define MFMA(a, b, c) __builtin_amdgcn_mfma_f32_16x16x32_bf16(a, b, c, 0, 0, 0)

__device__ __forceinline__ short f2bf(float x) {
    union { float f; unsigned u; } v; v.f = x;
    unsigned r = v.u + 0x7FFFu + ((v.u >> 16) & 1u);   // RNE
    return (short)(r >> 16);
}

// pack 4 f32 -> 4 bf16 (RNE) via v_cvt_pk_bf16_f32 (compiler-lowered)
__device__ __forceinline__ bf4 pk4(float a, float b, float c, float d) {
    union { __hip_bfloat162 h2[2]; bf4 v; } u;
    u.h2[0] = __float22bfloat162_rn(make_float2(a, b));
    u.h2[1] = __float22bfloat162_rn(make_float2(c, d));
    return u.v;
}

__device__ __forceinline__ bf8 cat44(bf4 lo, bf4 hi) {
    bf8 r;
    r[0] = lo[0]; r[1] = lo[1]; r[2] = lo[2]; r[3] = lo[3];
    r[4] = hi[0]; r[5] = hi[1]; r[6] = hi[2]; r[7] = hi[3];
    return r;
}

// 8 consecutive f32 from global -> bf16x8 fragment
__device__ __forceinline__ bf8 load8(const float* p) {
    const float4* q = (const float4*)p;
    float4 a = q[0], b = q[1];
    bf8 r;
    r[0] = f2bf(a.x); r[1] = f2bf(a.y); r[2] = f2bf(a.z); r[3] = f2bf(a.w);
    r[4] = f2bf(b.x); r[5] = f2bf(b.y); r[6] = f2bf(b.z); r[7] = f2bf(b.w);
    return r;
}

// async global->LDS, 16B per lane. lds dst must be wave-uniform base (+lane*16 implicit)
__device__ __forceinline__ void async16(const void* g, void* l) {
    __builtin_amdgcn_global_load_lds(
        (const __attribute__((address_space(1))) unsigned*)g,
        (__attribute__((address_space(3))) unsigned*)l, 16, 0, 0);
}

// ---------------- Kernel A: Wc [4096][128] f32 -> WcF fragment layout ----------------
__global__ __launch_bounds__(256) void k_wct(const float* __restrict__ Wc,
                                             unsigned short* __restrict__ WcF) {
    int f16 = blockIdx.x * 256 + threadIdx.x;   // 65536 fragments
    int l = f16 & 63, t = (f16 >> 6) & 3, nfA = (f16 >> 8) & 7, kc = f16 >> 11;
    int lrow = l & 15, lgrp = l >> 4;
    int kbase = kc * 128 + t * 32 + lgrp * 8;
    int n = nfA * 16 + lrow;
    bf8 v;
    #pragma unroll
    for (int j = 0; j < 8; ++j) v[j] = f2bf(Wc[(size_t)(kbase + j) * D_D + n]);
    *(bf8*)(WcF + (size_t)f16 * 8) = v;
}

// ---------------- Kernel A2: W[h][k][d] f32 -> WF fragment layout (Wk and Wv) --------
__global__ __launch_bounds__(256) void k_wt(const float* __restrict__ Wk,
        const float* __restrict__ Wv, unsigned short* __restrict__ WkF,
        unsigned short* __restrict__ WvF) {
    __shared__ unsigned short T[128][129];
    const int tid = threadIdx.x;
    const int h = blockIdx.x;
    const int job = blockIdx.y;
    const float* W = (job ? Wv : Wk) + (size_t)h * (D_D * D_D);
    unsigned short* WF = (job ? WvF : WkF) + (size_t)h * (D_D * D_D);

    #pragma unroll
    for (int i = 0; i < 64; ++i) {
        int flat = i * 256 + tid;       // k*128 + d
        T[flat >> 7][flat & 127] = (unsigned short)f2bf(W[flat]);
    }
    __syncthreads();
    #pragma unroll
    for (int j8 = 0; j8 < 8; ++j8) {
        int f16 = j8 * 256 + tid;
        int l = f16 & 63, t = (f16 >> 6) & 3, df = (f16 >> 8) & 7;
        int lrow = l & 15, lgrp = l >> 4;
        bf8 v;
        #pragma unroll
        for (int j = 0; j < 8; ++j) v[j] = (short)T[t * 32 + lgrp * 8 + j][df * 16 + lrow];
        *(bf8*)(WF + (size_t)f16 * 8) = v;
    }
}

// ---------------- Kernel B: FUSED K/V projections, packed 8B stores ------------------
// (byte-identical to R11/R12's version: others dropped 87->62us with it)
__global__ __launch_bounds__(256) void k_proj(const float* __restrict__ states,
        const unsigned short* __restrict__ WkF, const float* __restrict__ bk,
        const unsigned short* __restrict__ WvF, const float* __restrict__ bv,
        unsigned short* __restrict__ Kb, unsigned short* __restrict__ VTb) {
    const int tid = threadIdx.x;
    const int l = tid & 63, w = tid >> 6;
    const int lrow = l & 15, lgrp = l >> 4;
    const int bx = blockIdx.x;                  // (n*H + h)*32 + sc
    const int sc = bx & 31;
    const int nh = bx >> 5;
    const int h = nh & 31, n = nh >> 5;

    const float* srow = states + ((size_t)n * S_S + sc * 64 + w * 16 + lrow) * D_D;
    bf8 sf[4];
    #pragma unroll
    for (int t = 0; t < 4; ++t) sf[t] = load8(srow + t * 32 + lgrp * 8);

    // K job: swapped (A=WkF m=d, B=states n=s) -> 4 consecutive d per lane -> 8B stores
    {
        const unsigned short* WF = WkF + (size_t)h * (D_D * D_D);
        f4 acc[8];
        #pragma unroll
        for (int i = 0; i < 8; ++i) acc[i] = (f4)(0.f);
        #pragma unroll
        for (int mf = 0; mf < 8; ++mf) {
            #pragma unroll
            for (int t = 0; t < 4; ++t) {
                bf8 a = *(const bf8*)(WF + (((mf * 4 + t) * 64 + l) << 3));
                acc[mf] = MFMA(a, sf[t], acc[mf]);
            }
        }
        unsigned short* Kout = Kb + (size_t)(n * H_H + h) * S_S * D_D
                                  + (size_t)(sc * 64 + w * 16 + lrow) * D_D;
        #pragma unroll
        for (int mf = 0; mf < 8; ++mf) {
            int d0 = mf * 16 + lgrp * 4;
            float4 bb = *(const float4*)(bk + h * D_D + d0);
            bf4 kv = pk4((acc[mf][0] + bb.x) * SCALEK, (acc[mf][1] + bb.y) * SCALEK,
                         (acc[mf][2] + bb.z) * SCALEK, (acc[mf][3] + bb.w) * SCALEK);
            *(bf4*)(Kout + d0) = kv;
        }
    }
    // V job: non-swapped -> 4 consecutive permuted-s per lane -> 8B stores
    {
        const unsigned short* WF = WvF + (size_t)h * (D_D * D_D);
        f4 acc[8];
        #pragma unroll
        for (int i = 0; i < 8; ++i) acc[i] = (f4)(0.f);
        #pragma unroll
        for (int nf = 0; nf < 8; ++nf) {
            #pragma unroll
            for (int t = 0; t < 4; ++t) {
                bf8 b = *(const bf8*)(WF + (((nf * 4 + t) * 64 + l) << 3));
                acc[nf] = MFMA(sf[t], b, acc[nf]);
            }
        }
        unsigned short* Vout = VTb + (size_t)(n * H_H + h) * D_D * S_S;
        const int p0 = ((w >> 1) << 5) + (lgrp << 3) + ((w & 1) << 2);
        #pragma unroll
        for (int nf = 0; nf < 8; ++nf) {
            int d = nf * 16 + lrow;
            float bias = bv[h * D_D + d];
            bf4 vv = pk4(acc[nf][0] + bias, acc[nf][1] + bias,
                         acc[nf][2] + bias, acc[nf][3] + bias);
            *(bf4*)(Vout + (size_t)d * S_S + sc * 64 + p0) = vv;
        }
    }
}

// ---------------- Kernel C: flash attention (exact R10 config: best measured) -------
// R13 post-mortem: counted-vmcnt 3-buffer REGRESSED (184us) -- consistent with guide
// m131-m141: pipelining grafts on a 2-phase structure are neutral/negative. R10's
// config (2mf, chunk-32, 2-buf dbuf, (256,3) -> 12 waves/CU) is the empirical optimum
// of this family at 145us (~70% LDS-pipe duty). Reverted byte-identical.
__global__ __launch_bounds__(256, 3) void k_attn(const float* __restrict__ query,
        const unsigned short* __restrict__ Kb, const unsigned short* __restrict__ VTb,
        unsigned short* __restrict__ CTX) {
    // LDS 32KB: Kbuf[2] @ 0/8192 ([32 s][256B] swz), Vbuf[2] @ 16384/24576 ([128 d][64B] swz)
    __shared__ char smem[32768];
    const int tid = threadIdx.x;
    const int l = tid & 63, w = tid >> 6;          // w = 0..3
    const int lrow = l & 15, lgrp = l >> 4;

    // XCD swizzle: 1024 blocks, 8 XCDs -> 128 consecutive work-ids per XCD
    const int bid = blockIdx.x;
    const int bx = (bid & 7) * 128 + (bid >> 3);
    const int qt = bx & 15;
    const int nh = bx >> 4;
    const int h = nh & 31, n = nh >> 5;
    const int qbase = qt * 128 + w * 32;

    // Q fragments as B-operand of swapped QK^T
    bf8 qf[2][4];
    #pragma unroll
    for (int mf = 0; mf < 2; ++mf) {
        const float* qp = query + ((size_t)n * L_Q + qbase + mf * 16 + lrow) * D_D;
        #pragma unroll
        for (int t = 0; t < 4; ++t) qf[mf][t] = load8(qp + t * 32 + lgrp * 8);
    }

    f4 oacc[2][8];   // O^T[d][q]: lane holds rows d = df*16 + 4*lgrp + r, col q = lrow
    #pragma unroll
    for (int mf = 0; mf < 2; ++mf)
        #pragma unroll
        for (int df = 0; df < 8; ++df) oacc[mf][df] = (f4)(0.f);
    float rsum[2] = {0.f, 0.f};

    const char* Kg = (const char*)(Kb + (size_t)(n * H_H + h) * S_S * D_D);
    const char* Vg = (const char*)(VTb + (size_t)(n * H_H + h) * D_D * S_S);

    // stage 32-s chunk sc2 (0..63): K 8KB + V 8KB, 4 async16 per wave
    auto stage = [&](int c, int sc2) {
        char* Kl = smem + c * 8192;
        char* Vl = smem + 16384 + c * 8192;
        #pragma unroll
        for (int i = 0; i < 2; ++i) {
            int kop = w * 2 + i;                 // 0..7
            int o = kop * 1024 + l * 16;         // 0..8191
            int r = o >> 8;                      // s-row 0..31
            int b = (o & 255) ^ ((r & 7) << 4);
            async16(Kg + (size_t)(sc2 * 32 + r) * 256 + b, Kl + kop * 1024);
        }
        #pragma unroll
        for (int i = 0; i < 2; ++i) {
            int vop = w * 2 + i;
            int o = vop * 1024 + l * 16;         // 0..8191
            int drow = o >> 6;                   // d-row 0..127 (64B rows)
            int b = (o & 63) ^ (((drow >> 1) & 3) << 4);
            async16(Vg + (size_t)drow * 4096 + sc2 * 64 + b, Vl + vop * 1024);
        }
    };

    // one s-iteration with STATIC buffer index
    auto iter = [&](int cur, int sc2, bool prefetch) {
        if (prefetch) stage(cur ^ 1, sc2 + 1);
        const char* Klds = smem + cur * 8192;
        const char* Vlds = smem + 16384 + cur * 8192;

        // QK^T swapped: sacc[mf][nf] over 32 s
        f4 sacc[2][2];
        #pragma unroll
        for (int mf = 0; mf < 2; ++mf)
            #pragma unroll
            for (int nf = 0; nf < 2; ++nf) sacc[mf][nf] = (f4)(0.f);
        __builtin_amdgcn_s_setprio(1);
        #pragma unroll
        for (int nf = 0; nf < 2; ++nf) {
            int srow = nf * 16 + lrow;
            int swz = (srow & 7) << 4;
            #pragma unroll
            for (int t = 0; t < 4; ++t) {
                bf8 kb = *(const bf8*)(Klds + srow * 256 + (((t * 32 + lgrp * 8) * 2) ^ swz));
                sacc[0][nf] = MFMA(kb, qf[0][t], sacc[0][nf]);
                sacc[1][nf] = MFMA(kb, qf[1][t], sacc[1][nf]);
            }
        }
        __builtin_amdgcn_s_setprio(0);

        // softmax: exp2 + lane-local sum + pack into ONE K=32 B-operand per mf
        bf8 pf[2];
        #pragma unroll
        for (int mf = 0; mf < 2; ++mf) {
            bf4 pblk[2];
            #pragma unroll
            for (int nf = 0; nf < 2; ++nf) {
                float p0 = __builtin_amdgcn_exp2f(sacc[mf][nf][0]);
                float p1 = __builtin_amdgcn_exp2f(sacc[mf][nf][1]);
                float p2 = __builtin_amdgcn_exp2f(sacc[mf][nf][2]);
                float p3 = __builtin_amdgcn_exp2f(sacc[mf][nf][3]);
                rsum[mf] += (p0 + p1) + (p2 + p3);
                pblk[nf] = pk4(p0, p1, p2, p3);
            }
            pf[mf] = cat44(pblk[0], pblk[1]);
        }

        // PV swapped, K=32: V^T s-permuted -> ONE conflict-free b128 per df
        __builtin_amdgcn_s_setprio(1);
        #pragma unroll
        for (int df = 0; df < 8; ++df) {
            int drow = df * 16 + lrow;
            bf8 vf = *(const bf8*)(Vlds + drow * 64 + ((lgrp * 16) ^ (((drow >> 1) & 3) << 4)));
            oacc[0][df] = MFMA(vf, pf[0], oacc[0][df]);
            oacc[1][df] = MFMA(vf, pf[1], oacc[1][df]);
        }
        __builtin_amdgcn_s_setprio(0);
        __syncthreads();    // implicit vmcnt(0): prefetch landed; LDS reuse safe
    };

    stage(0, 0);
    __syncthreads();
    for (int s2 = 0; s2 < 64; s2 += 2) {
        iter(0, s2, true);
        iter(1, s2 + 1, s2 + 1 < 63);
    }

    // reduce rsum over the 4 lane-groups; q = lrow stays lane-local
    float rinv[2];
    #pragma unroll
    for (int mf = 0; mf < 2; ++mf) {
        float v = rsum[mf];
        v += __shfl_xor(v, 16, 64);
        v += __shfl_xor(v, 32, 64);
        rinv[mf] = 1.f / v;
    }
    #pragma unroll
    for (int mf = 0; mf < 2; ++mf) {
        int qrow = qbase + mf * 16 + lrow;
        unsigned short* crow = CTX + (size_t)(n * L_Q + qrow) * 4096 + h * D_D;
        #pragma unroll
        for (int df = 0; df < 8; ++df) {
            bf4 o = pk4(oacc[mf][df][0] * rinv[mf], oacc[mf][df][1] * rinv[mf],
                        oacc[mf][df][2] * rinv[mf], oacc[mf][df][3] * rinv[mf]);
            *(bf4*)(crow + df * 16 + lgrp * 4) = o;
        }
    }
}

// ---------------- Kernel E: out = CTX @ Wc + bc (M=16, 256 blocks, coalesced WcF) ---
__global__ __launch_bounds__(256) void k_out(const unsigned short* __restrict__ CTX,
        const unsigned short* __restrict__ WcF, const float* __restrict__ bc,
        float* __restrict__ out) {
    __shared__ char Alds[8192];   // 2 x [16][256B] swizzled
    const int tid = threadIdx.x;
    const int l = tid & 63, w = tid >> 6;
    const int lrow = l & 15, lgrp = l >> 4;
    const int m0 = blockIdx.x * 16;      // 256 blocks
    const char* Ag = (const char*)(CTX + (size_t)m0 * 4096);

    auto stage = [&](int c, int kc) {
        int o = w * 1024 + l * 16;
        int r = o >> 8;
        int b = (o & 255) ^ ((r & 7) << 4);
        async16(Ag + (size_t)r * 8192 + kc * 256 + b, Alds + c * 4096 + w * 1024);
    };

    f4 acc[2];
    acc[0] = (f4)(0.f); acc[1] = (f4)(0.f);
    stage(0, 0);
    __syncthreads();
    int cur = 0;
    for (int kc = 0; kc < 32; ++kc) {
        if (kc < 31) stage(cur ^ 1, kc + 1);
        const char* Ac = Alds + cur * 4096;
        #pragma unroll
        for (int t = 0; t < 4; ++t) {
            int swz = (lrow & 7) << 4;
            bf8 a = *(const bf8*)(Ac + lrow * 256 + (((t * 32 + lgrp * 8) * 2) ^ swz));
            #pragma unroll
            for (int nf = 0; nf < 2; ++nf) {
                int nfA = w * 2 + nf;
                bf8 b = *(const bf8*)(WcF + ((size_t)(((kc * 8 + nfA) * 4 + t) * 64 + l) << 3));
                acc[nf] = MFMA(a, b, acc[nf]);
            }
        }
        __syncthreads();
        cur ^= 1;
    }
    #pragma unroll
    for (int nf = 0; nf < 2; ++nf) {
        int nc = w * 32 + nf * 16 + lrow;
        float bias = bc[nc];
        #pragma unroll
        for (int r = 0; r < 4; ++r)
            out[(size_t)(m0 + lgrp * 4 + r) * D_D + nc] = acc[nf][r] + bias;
    }
}

extern "C" void kernel_launch(void* const* d_in, const int* in_sizes, int n_in,
                              void* d_out, int out_size, void* d_ws, size_t ws_size,
                              hipStream_t stream) {
    const float* query  = (const float*)d_in[0];
    const float* states = (const float*)d_in[1];
    const float* Wk = (const float*)d_in[2];
    const float* bk = (const float*)d_in[3];
    const float* Wv = (const float*)d_in[4];
    const float* bv = (const float*)d_in[5];
    const float* Wc = (const float*)d_in[6];
    const float* bc = (const float*)d_in[7];
    float* out = (float*)d_out;

    // workspace (bf16): Kb 32MB | VTb 32MB | CTX 32MB | WcF 1MB.
    // WkF/WvF (1MB each) OVERLAP the CTX region: consumed by k_proj before
    // k_attn writes CTX -> no extra ws.
    char* ws = (char*)d_ws;
    unsigned short* Kb  = (unsigned short*)(ws);
    unsigned short* VTb = (unsigned short*)(ws + 33554432);
    unsigned short* CTX = (unsigned short*)(ws + 67108864);
    unsigned short* WkF = (unsigned short*)(ws + 67108864);
    unsigned short* WvF = (unsigned short*)(ws + 67108864 + 1048576);
    unsigned short* WcF = (unsigned short*)(ws + 100663296);

    k_wct<<<256, 256, 0, stream>>>(Wc, WcF);
    dim3 gw(32, 2);
    k_wt<<<gw, 256, 0, stream>>>(Wk, Wv, WkF, WvF);
    k_proj<<<2048, 256, 0, stream>>>(states, WkF, bk, WvF, bv, Kb, VTb);
    k_attn<<<1024, 256, 0, stream>>>(query, Kb, VTb, CTX);
    k_out<<<256, 256, 0, stream>>>(CTX, WcF, bc, out);
}

// Round 15
// 218.401 us; speedup vs baseline: 1.1528x; 1.0117x over previous
//
#include <hip/hip_runtime.h>
#include <hip/hip_bf16.h>

// Problem constants: N=2, L=2048, S=2048, D=128, H=32
#define N_B 2
#define L_Q 2048
#define S_S 2048
#define D_D 128
#define H_H 32
// 1/sqrt(128) * log2(e), folded into K projection so attn uses exp2 directly
#define SCALEK (0.08838834764831845f * 1.4426950408889634f)

typedef __attribute__((ext_vector_type(8))) short bf8;   // 8 bf16 (4 VGPR)
typedef __attribute__((ext_vector_type(4))) short bf4;   // 4 bf16 (2 VGPR)
typedef __attribute__((ext_vector_type(4))) float f4;    // 4 f32

#define MFMA(a, b, c) __builtin_amdgcn_mfma_f32_16x16x32_bf16(a, b, c, 0, 0, 0)

__device__ __forceinline__ short f2bf(float x) {
    union { float f; unsigned u; } v; v.f = x;
    unsigned r = v.u + 0x7FFFu + ((v.u >> 16) & 1u);   // RNE
    return (short)(r >> 16);
}

// pack 4 f32 -> 4 bf16 (RNE) via v_cvt_pk_bf16_f32 (compiler-lowered)
__device__ __forceinline__ bf4 pk4(float a, float b, float c, float d) {
    union { __hip_bfloat162 h2[2]; bf4 v; } u;
    u.h2[0] = __float22bfloat162_rn(make_float2(a, b));
    u.h2[1] = __float22bfloat162_rn(make_float2(c, d));
    return u.v;
}

__device__ __forceinline__ bf8 cat44(bf4 lo, bf4 hi) {
    bf8 r;
    r[0] = lo[0]; r[1] = lo[1]; r[2] = lo[2]; r[3] = lo[3];
    r[4] = hi[0]; r[5] = hi[1]; r[6] = hi[2]; r[7] = hi[3];
    return r;
}

// 8 consecutive f32 from global -> bf16x8 fragment
__device__ __forceinline__ bf8 load8(const float* p) {
    const float4* q = (const float4*)p;
    float4 a = q[0], b = q[1];
    bf8 r;
    r[0] = f2bf(a.x); r[1] = f2bf(a.y); r[2] = f2bf(a.z); r[3] = f2bf(a.w);
    r[4] = f2bf(b.x); r[5] = f2bf(b.y); r[6] = f2bf(b.z); r[7] = f2bf(b.w);
    return r;
}

// async global->LDS, 16B per lane. lds dst must be wave-uniform base (+lane*16 implicit)
__device__ __forceinline__ void async16(const void* g, void* l) {
    __builtin_amdgcn_global_load_lds(
        (const __attribute__((address_space(1))) unsigned*)g,
        (__attribute__((address_space(3))) unsigned*)l, 16, 0, 0);
}

// ---------------- Kernel A (merged): weight prep for Wc (y=0) and Wk/Wv (y=1) -------
// y=0: Wc [4096][128] f32 -> WcF fragment layout (256 blocks)
// y=1: blocks 0-31 -> WkF, blocks 32-63 -> WvF ([h][k][d] f32 -> fragment layout)
__global__ __launch_bounds__(256) void k_wprep(const float* __restrict__ Wc,
        unsigned short* __restrict__ WcF, const float* __restrict__ Wk,
        const float* __restrict__ Wv, unsigned short* __restrict__ WkF,
        unsigned short* __restrict__ WvF) {
    const int tid = threadIdx.x;
    if (blockIdx.y == 0) {
        int f16 = blockIdx.x * 256 + tid;   // 65536 fragments
        int l = f16 & 63, t = (f16 >> 6) & 3, nfA = (f16 >> 8) & 7, kc = f16 >> 11;
        int lrow = l & 15, lgrp = l >> 4;
        int kbase = kc * 128 + t * 32 + lgrp * 8;
        int n = nfA * 16 + lrow;
        bf8 v;
        #pragma unroll
        for (int j = 0; j < 8; ++j) v[j] = f2bf(Wc[(size_t)(kbase + j) * D_D + n]);
        *(bf8*)(WcF + (size_t)f16 * 8) = v;
        return;
    }
    // y == 1: W transpose to fragment layout
    if (blockIdx.x >= 64) return;
    __shared__ unsigned short T[128][129];
    const int h = blockIdx.x & 31;
    const int job = blockIdx.x >> 5;
    const float* W = (job ? Wv : Wk) + (size_t)h * (D_D * D_D);
    unsigned short* WF = (job ? WvF : WkF) + (size_t)h * (D_D * D_D);

    #pragma unroll
    for (int i = 0; i < 64; ++i) {
        int flat = i * 256 + tid;       // k*128 + d
        T[flat >> 7][flat & 127] = (unsigned short)f2bf(W[flat]);
    }
    __syncthreads();
    #pragma unroll
    for (int j8 = 0; j8 < 8; ++j8) {
        int f16 = j8 * 256 + tid;
        int l = f16 & 63, t = (f16 >> 6) & 3, df = (f16 >> 8) & 7;
        int lrow = l & 15, lgrp = l >> 4;
        bf8 v;
        #pragma unroll
        for (int j = 0; j < 8; ++j) v[j] = (short)T[t * 32 + lgrp * 8 + j][df * 16 + lrow];
        *(bf8*)(WF + (size_t)f16 * 8) = v;
    }
}

// ---------------- Kernel B: FUSED K/V projections, packed 8B stores ------------------
// (byte-identical to R11/R12/R14's version)
__global__ __launch_bounds__(256) void k_proj(const float* __restrict__ states,
        const unsigned short* __restrict__ WkF, const float* __restrict__ bk,
        const unsigned short* __restrict__ WvF, const float* __restrict__ bv,
        unsigned short* __restrict__ Kb, unsigned short* __restrict__ VTb) {
    const int tid = threadIdx.x;
    const int l = tid & 63, w = tid >> 6;
    const int lrow = l & 15, lgrp = l >> 4;
    const int bx = blockIdx.x;                  // (n*H + h)*32 + sc
    const int sc = bx & 31;
    const int nh = bx >> 5;
    const int h = nh & 31, n = nh >> 5;

    const float* srow = states + ((size_t)n * S_S + sc * 64 + w * 16 + lrow) * D_D;
    bf8 sf[4];
    #pragma unroll
    for (int t = 0; t < 4; ++t) sf[t] = load8(srow + t * 32 + lgrp * 8);

    // K job: swapped (A=WkF m=d, B=states n=s) -> 4 consecutive d per lane -> 8B stores
    {
        const unsigned short* WF = WkF + (size_t)h * (D_D * D_D);
        f4 acc[8];
        #pragma unroll
        for (int i = 0; i < 8; ++i) acc[i] = (f4)(0.f);
        #pragma unroll
        for (int mf = 0; mf < 8; ++mf) {
            #pragma unroll
            for (int t = 0; t < 4; ++t) {
                bf8 a = *(const bf8*)(WF + (((mf * 4 + t) * 64 + l) << 3));
                acc[mf] = MFMA(a, sf[t], acc[mf]);
            }
        }
        unsigned short* Kout = Kb + (size_t)(n * H_H + h) * S_S * D_D
                                  + (size_t)(sc * 64 + w * 16 + lrow) * D_D;
        #pragma unroll
        for (int mf = 0; mf < 8; ++mf) {
            int d0 = mf * 16 + lgrp * 4;
            float4 bb = *(const float4*)(bk + h * D_D + d0);
            bf4 kv = pk4((acc[mf][0] + bb.x) * SCALEK, (acc[mf][1] + bb.y) * SCALEK,
                         (acc[mf][2] + bb.z) * SCALEK, (acc[mf][3] + bb.w) * SCALEK);
            *(bf4*)(Kout + d0) = kv;
        }
    }
    // V job: non-swapped -> 4 consecutive permuted-s per lane -> 8B stores
    {
        const unsigned short* WF = WvF + (size_t)h * (D_D * D_D);
        f4 acc[8];
        #pragma unroll
        for (int i = 0; i < 8; ++i) acc[i] = (f4)(0.f);
        #pragma unroll
        for (int nf = 0; nf < 8; ++nf) {
            #pragma unroll
            for (int t = 0; t < 4; ++t) {
                bf8 b = *(const bf8*)(WF + (((nf * 4 + t) * 64 + l) << 3));
                acc[nf] = MFMA(sf[t], b, acc[nf]);
            }
        }
        unsigned short* Vout = VTb + (size_t)(n * H_H + h) * D_D * S_S;
        const int p0 = ((w >> 1) << 5) + (lgrp << 3) + ((w & 1) << 2);
        #pragma unroll
        for (int nf = 0; nf < 8; ++nf) {
            int d = nf * 16 + lrow;
            float bias = bv[h * D_D + d];
            bf4 vv = pk4(acc[nf][0] + bias, acc[nf][1] + bias,
                         acc[nf][2] + bias, acc[nf][3] + bias);
            *(bf4*)(Vout + (size_t)d * S_S + sc * 64 + p0) = vv;
        }
    }
}

// ---------------- Kernel C: flash attention (R10 config, setprio REMOVED) -----------
// Single-variable test: m190 showed s_setprio(1) around MFMA HURTS barrier-synced
// lockstep structures (GEMM -14 TF); our 4-wave barrier-locked block matches that
// case, not m191's independent-wave attn. Everything else identical to R14.
__global__ __launch_bounds__(256, 3) void k_attn(const float* __restrict__ query,
        const unsigned short* __restrict__ Kb, const unsigned short* __restrict__ VTb,
        unsigned short* __restrict__ CTX) {
    // LDS 32KB: Kbuf[2] @ 0/8192 ([32 s][256B] swz), Vbuf[2] @ 16384/24576 ([128 d][64B] swz)
    __shared__ char smem[32768];
    const int tid = threadIdx.x;
    const int l = tid & 63, w = tid >> 6;          // w = 0..3
    const int lrow = l & 15, lgrp = l >> 4;

    // XCD swizzle: 1024 blocks, 8 XCDs -> 128 consecutive work-ids per XCD
    const int bid = blockIdx.x;
    const int bx = (bid & 7) * 128 + (bid >> 3);
    const int qt = bx & 15;
    const int nh = bx >> 4;
    const int h = nh & 31, n = nh >> 5;
    const int qbase = qt * 128 + w * 32;

    // Q fragments as B-operand of swapped QK^T
    bf8 qf[2][4];
    #pragma unroll
    for (int mf = 0; mf < 2; ++mf) {
        const float* qp = query + ((size_t)n * L_Q + qbase + mf * 16 + lrow) * D_D;
        #pragma unroll
        for (int t = 0; t < 4; ++t) qf[mf][t] = load8(qp + t * 32 + lgrp * 8);
    }

    f4 oacc[2][8];   // O^T[d][q]: lane holds rows d = df*16 + 4*lgrp + r, col q = lrow
    #pragma unroll
    for (int mf = 0; mf < 2; ++mf)
        #pragma unroll
        for (int df = 0; df < 8; ++df) oacc[mf][df] = (f4)(0.f);
    float rsum[2] = {0.f, 0.f};

    const char* Kg = (const char*)(Kb + (size_t)(n * H_H + h) * S_S * D_D);
    const char* Vg = (const char*)(VTb + (size_t)(n * H_H + h) * D_D * S_S);

    // stage 32-s chunk sc2 (0..63): K 8KB + V 8KB, 4 async16 per wave
    auto stage = [&](int c, int sc2) {
        char* Kl = smem + c * 8192;
        char* Vl = smem + 16384 + c * 8192;
        #pragma unroll
        for (int i = 0; i < 2; ++i) {
            int kop = w * 2 + i;                 // 0..7
            int o = kop * 1024 + l * 16;         // 0..8191
            int r = o >> 8;                      // s-row 0..31
            int b = (o & 255) ^ ((r & 7) << 4);
            async16(Kg + (size_t)(sc2 * 32 + r) * 256 + b, Kl + kop * 1024);
        }
        #pragma unroll
        for (int i = 0; i < 2; ++i) {
            int vop = w * 2 + i;
            int o = vop * 1024 + l * 16;         // 0..8191
            int drow = o >> 6;                   // d-row 0..127 (64B rows)
            int b = (o & 63) ^ (((drow >> 1) & 3) << 4);
            async16(Vg + (size_t)drow * 4096 + sc2 * 64 + b, Vl + vop * 1024);
        }
    };

    // one s-iteration with STATIC buffer index
    auto iter = [&](int cur, int sc2, bool prefetch) {
        if (prefetch) stage(cur ^ 1, sc2 + 1);
        const char* Klds = smem + cur * 8192;
        const char* Vlds = smem + 16384 + cur * 8192;

        // QK^T swapped: sacc[mf][nf] over 32 s
        f4 sacc[2][2];
        #pragma unroll
        for (int mf = 0; mf < 2; ++mf)
            #pragma unroll
            for (int nf = 0; nf < 2; ++nf) sacc[mf][nf] = (f4)(0.f);
        #pragma unroll
        for (int nf = 0; nf < 2; ++nf) {
            int srow = nf * 16 + lrow;
            int swz = (srow & 7) << 4;
            #pragma unroll
            for (int t = 0; t < 4; ++t) {
                bf8 kb = *(const bf8*)(Klds + srow * 256 + (((t * 32 + lgrp * 8) * 2) ^ swz));
                sacc[0][nf] = MFMA(kb, qf[0][t], sacc[0][nf]);
                sacc[1][nf] = MFMA(kb, qf[1][t], sacc[1][nf]);
            }
        }

        // softmax: exp2 + lane-local sum + pack into ONE K=32 B-operand per mf
        bf8 pf[2];
        #pragma unroll
        for (int mf = 0; mf < 2; ++mf) {
            bf4 pblk[2];
            #pragma unroll
            for (int nf = 0; nf < 2; ++nf) {
                float p0 = __builtin_amdgcn_exp2f(sacc[mf][nf][0]);
                float p1 = __builtin_amdgcn_exp2f(sacc[mf][nf][1]);
                float p2 = __builtin_amdgcn_exp2f(sacc[mf][nf][2]);
                float p3 = __builtin_amdgcn_exp2f(sacc[mf][nf][3]);
                rsum[mf] += (p0 + p1) + (p2 + p3);
                pblk[nf] = pk4(p0, p1, p2, p3);
            }
            pf[mf] = cat44(pblk[0], pblk[1]);
        }

        // PV swapped, K=32: V^T s-permuted -> ONE conflict-free b128 per df
        #pragma unroll
        for (int df = 0; df < 8; ++df) {
            int drow = df * 16 + lrow;
            bf8 vf = *(const bf8*)(Vlds + drow * 64 + ((lgrp * 16) ^ (((drow >> 1) & 3) << 4)));
            oacc[0][df] = MFMA(vf, pf[0], oacc[0][df]);
            oacc[1][df] = MFMA(vf, pf[1], oacc[1][df]);
        }
        __syncthreads();    // implicit vmcnt(0): prefetch landed; LDS reuse safe
    };

    stage(0, 0);
    __syncthreads();
    for (int s2 = 0; s2 < 64; s2 += 2) {
        iter(0, s2, true);
        iter(1, s2 + 1, s2 + 1 < 63);
    }

    // reduce rsum over the 4 lane-groups; q = lrow stays lane-local
    float rinv[2];
    #pragma unroll
    for (int mf = 0; mf < 2; ++mf) {
        float v = rsum[mf];
        v += __shfl_xor(v, 16, 64);
        v += __shfl_xor(v, 32, 64);
        rinv[mf] = 1.f / v;
    }
    #pragma unroll
    for (int mf = 0; mf < 2; ++mf) {
        int qrow = qbase + mf * 16 + lrow;
        unsigned short* crow = CTX + (size_t)(n * L_Q + qrow) * 4096 + h * D_D;
        #pragma unroll
        for (int df = 0; df < 8; ++df) {
            bf4 o = pk4(oacc[mf][df][0] * rinv[mf], oacc[mf][df][1] * rinv[mf],
                        oacc[mf][df][2] * rinv[mf], oacc[mf][df][3] * rinv[mf]);
            *(bf4*)(crow + df * 16 + lgrp * 4) = o;
        }
    }
}

// ---------------- Kernel E: out = CTX @ Wc + bc (M=16, 256 blocks, coalesced WcF) ---
__global__ __launch_bounds__(256) void k_out(const unsigned short* __restrict__ CTX,
        const unsigned short* __restrict__ WcF, const float* __restrict__ bc,
        float* __restrict__ out) {
    __shared__ char Alds[8192];   // 2 x [16][256B] swizzled
    const int tid = threadIdx.x;
    const int l = tid & 63, w = tid >> 6;
    const int lrow = l & 15, lgrp = l >> 4;
    const int m0 = blockIdx.x * 16;      // 256 blocks
    const char* Ag = (const char*)(CTX + (size_t)m0 * 4096);

    auto stage = [&](int c, int kc) {
        int o = w * 1024 + l * 16;
        int r = o >> 8;
        int b = (o & 255) ^ ((r & 7) << 4);
        async16(Ag + (size_t)r * 8192 + kc * 256 + b, Alds + c * 4096 + w * 1024);
    };

    f4 acc[2];
    acc[0] = (f4)(0.f); acc[1] = (f4)(0.f);
    stage(0, 0);
    __syncthreads();
    int cur = 0;
    for (int kc = 0; kc < 32; ++kc) {
        if (kc < 31) stage(cur ^ 1, kc + 1);
        const char* Ac = Alds + cur * 4096;
        #pragma unroll
        for (int t = 0; t < 4; ++t) {
            int swz = (lrow & 7) << 4;
            bf8 a = *(const bf8*)(Ac + lrow * 256 + (((t * 32 + lgrp * 8) * 2) ^ swz));
            #pragma unroll
            for (int nf = 0; nf < 2; ++nf) {
                int nfA = w * 2 + nf;
                bf8 b = *(const bf8*)(WcF + ((size_t)(((kc * 8 + nfA) * 4 + t) * 64 + l) << 3));
                acc[nf] = MFMA(a, b, acc[nf]);
            }
        }
        __syncthreads();
        cur ^= 1;
    }
    #pragma unroll
    for (int nf = 0; nf < 2; ++nf) {
        int nc = w * 32 + nf * 16 + lrow;
        float bias = bc[nc];
        #pragma unroll
        for (int r = 0; r < 4; ++r)
            out[(size_t)(m0 + lgrp * 4 + r) * D_D + nc] = acc[nf][r] + bias;
    }
}

extern "C" void kernel_launch(void* const* d_in, const int* in_sizes, int n_in,
                              void* d_out, int out_size, void* d_ws, size_t ws_size,
                              hipStream_t stream) {
    const float* query  = (const float*)d_in[0];
    const float* states = (const float*)d_in[1];
    const float* Wk = (const float*)d_in[2];
    const float* bk = (const float*)d_in[3];
    const float* Wv = (const float*)d_in[4];
    const float* bv = (const float*)d_in[5];
    const float* Wc = (const float*)d_in[6];
    const float* bc = (const float*)d_in[7];
    float* out = (float*)d_out;

    // workspace (bf16): Kb 32MB | VTb 32MB | CTX 32MB | WcF 1MB.
    // WkF/WvF (1MB each) OVERLAP the CTX region: consumed by k_proj before
    // k_attn writes CTX -> no extra ws.
    char* ws = (char*)d_ws;
    unsigned short* Kb  = (unsigned short*)(ws);
    unsigned short* VTb = (unsigned short*)(ws + 33554432);
    unsigned short* CTX = (unsigned short*)(ws + 67108864);
    unsigned short* WkF = (unsigned short*)(ws + 67108864);
    unsigned short* WvF = (unsigned short*)(ws + 67108864 + 1048576);
    unsigned short* WcF = (unsigned short*)(ws + 100663296);

    dim3 gp(256, 2);
    k_wprep<<<gp, 256, 0, stream>>>(Wc, WcF, Wk, Wv, WkF, WvF);
    k_proj<<<2048, 256, 0, stream>>>(states, WkF, bk, WvF, bv, Kb, VTb);
    k_attn<<<1024, 256, 0, stream>>>(query, Kb, VTb, CTX);
    k_out<<<256, 256, 0, stream>>>(CTX, WcF, bc, out);
}